// Round 1
// baseline (435.065 us; speedup 1.0000x reference)
//
#include <hip/hip_runtime.h>
#include <hip/hip_bf16.h>
#include <cstdint>
#include <cstddef>

#define B_    4
#define T_    2048
#define DIN_  1024
#define DEMB_ 1024
#define H_    16
#define HD_   64
#define M_    8192        // B_*T_
#define NQKV_ 3072        // 3*DEMB_

typedef __bf16 bf16_t;
typedef __bf16 bf16x8 __attribute__((ext_vector_type(8)));
typedef __bf16 bf16x4 __attribute__((ext_vector_type(4)));
typedef float  f32x4  __attribute__((ext_vector_type(4)));

__device__ __forceinline__ bf16_t tob(float f) {
  __hip_bfloat16 h = __float2bfloat16(f);
  return __builtin_bit_cast(bf16_t, h);
}

__device__ __forceinline__ f32x4 mfma16(bf16x8 a, bf16x8 b, f32x4 c) {
  return __builtin_amdgcn_mfma_f32_16x16x32_bf16(a, b, c, 0, 0, 0);
}

__device__ __forceinline__ void gload16(const void* g, void* l) {
  __builtin_amdgcn_global_load_lds((const __attribute__((address_space(1))) void*)g,
                                   (__attribute__((address_space(3))) void*)l, 16, 0, 0);
}

// ---------------- fp32 -> bf16 cast (4 elems/thread) ----------------
__global__ __launch_bounds__(256) void cast_kernel(const float* __restrict__ in,
                                                   bf16_t* __restrict__ out) {
  size_t i = (size_t)blockIdx.x * 256 + threadIdx.x;
  float4 v = ((const float4*)in)[i];
  bf16x4 o;
  o[0] = tob(v.x); o[1] = tob(v.y); o[2] = tob(v.z); o[3] = tob(v.w);
  ((bf16x4*)out)[i] = o;
}

// ---------------- GEMM1: qkv = x * w_qkv^T, scatter to Q/K/V ----------------
// A [M_, DIN_] bf16 row-major, Bm [NQKV_, DIN_] bf16 row-major (B^T gemm)
__global__ __launch_bounds__(256) void gemm_qkv_kernel(const bf16_t* __restrict__ A,
                                                       const bf16_t* __restrict__ Bm,
                                                       bf16_t* __restrict__ qb,
                                                       bf16_t* __restrict__ kb,
                                                       bf16_t* __restrict__ vb) {
  constexpr int K = DIN_;
  __shared__ __align__(16) bf16_t As[128 * 32];
  __shared__ __align__(16) bf16_t Bs[128 * 32];
  const int tid = threadIdx.x, w = tid >> 6, l = tid & 63;
  const int lh = l >> 4, lr = l & 15;
  const int m0 = blockIdx.y * 128, n0 = blockIdx.x * 128;
  const int ar0 = (w >> 1) * 64, bc0 = (w & 1) * 64;
  f32x4 acc[4][4] = {};
  for (int k0 = 0; k0 < K; k0 += 32) {
#pragma unroll
    for (int i = 0; i < 2; ++i) {
      const int c = i * 256 + w * 64 + l;
      const int row = c >> 2, col = (c & 3) * 8;
      gload16(A  + (size_t)(m0 + row) * K + k0 + col, (char*)As + (size_t)(i * 256 + w * 64) * 16);
      gload16(Bm + (size_t)(n0 + row) * K + k0 + col, (char*)Bs + (size_t)(i * 256 + w * 64) * 16);
    }
    __syncthreads();
    bf16x8 af[4], bfv[4];
#pragma unroll
    for (int mi = 0; mi < 4; ++mi) af[mi]  = *(const bf16x8*)&As[(ar0 + mi * 16 + lr) * 32 + lh * 8];
#pragma unroll
    for (int ni = 0; ni < 4; ++ni) bfv[ni] = *(const bf16x8*)&Bs[(bc0 + ni * 16 + lr) * 32 + lh * 8];
#pragma unroll
    for (int mi = 0; mi < 4; ++mi)
#pragma unroll
      for (int ni = 0; ni < 4; ++ni)
        acc[mi][ni] = mfma16(af[mi], bfv[ni], acc[mi][ni]);
    __syncthreads();
  }
  // epilogue: C[gm][gn], gn = h*192 + s ; s<64 -> Q, <128 -> K, else V ; dest [B,H,T,64]
#pragma unroll
  for (int mi = 0; mi < 4; ++mi) {
#pragma unroll
    for (int r = 0; r < 4; ++r) {
      const int gm = m0 + ar0 + mi * 16 + lh * 4 + r;
      const int bb = gm >> 11, t = gm & (T_ - 1);
#pragma unroll
      for (int ni = 0; ni < 4; ++ni) {
        const int gn = n0 + bc0 + ni * 16 + lr;
        const int h = gn / 192, s = gn - h * 192;
        const size_t idx = (((size_t)bb * H_ + h) * T_ + t) * HD_;
        const bf16_t bv = tob(acc[mi][ni][r]);
        if (s < 64)       qb[idx + s] = bv;
        else if (s < 128) kb[idx + s - 64] = bv;
        else              vb[idx + s - 128] = bv;
      }
    }
  }
}

// ---------------- flash attention, causal, per (b,h) ----------------
__global__ __launch_bounds__(256) void attn_kernel(const bf16_t* __restrict__ qb,
                                                   const bf16_t* __restrict__ kb,
                                                   const bf16_t* __restrict__ vb,
                                                   bf16_t* __restrict__ ob) {
  __shared__ __align__(16) bf16_t Kl[64 * 72];      // [kv][d] pad 72
  __shared__ __align__(16) bf16_t Vt[64 * 72];      // [d][kv] pad 72
  __shared__ __align__(16) bf16_t Pl[4][16 * 72];   // per-wave P tile
  const int qt = blockIdx.x, bh = blockIdx.y;
  const int tid = threadIdx.x, w = tid >> 6, l = tid & 63;
  const int lh = l >> 4, lr = l & 15;
  const size_t base = (size_t)bh * T_ * HD_;
  const bf16_t* Qg = qb + base;
  const bf16_t* Kg = kb + base;
  const bf16_t* Vg = vb + base;
  const int qrow_a = qt * 64 + w * 16 + lr;         // A-frag row
  bf16x8 qf0 = *(const bf16x8*)&Qg[(size_t)qrow_a * HD_ + lh * 8];
  bf16x8 qf1 = *(const bf16x8*)&Qg[(size_t)qrow_a * HD_ + 32 + lh * 8];
  const int qrow_d = qt * 64 + w * 16 + lh * 4;     // D-layout row base
  f32x4 acc_o[4] = {};
  float mrun[4], lrun[4];
#pragma unroll
  for (int r = 0; r < 4; ++r) { mrun[r] = -__builtin_inff(); lrun[r] = 0.f; }

  for (int kt = 0; kt <= qt; ++kt) {
    __syncthreads();
    // stage K tile and transposed V tile
#pragma unroll
    for (int i = 0; i < 2; ++i) {
      const int c = i * 256 + tid;
      const int row = c >> 3, col = (c & 7) * 8;
      const size_t go = (size_t)(kt * 64 + row) * HD_ + col;
      *(bf16x8*)&Kl[row * 72 + col] = *(const bf16x8*)&Kg[go];
      bf16x8 vv = *(const bf16x8*)&Vg[go];
#pragma unroll
      for (int j = 0; j < 8; ++j) Vt[(col + j) * 72 + row] = vv[j];
    }
    __syncthreads();

    // S = Q K^T  (per-wave 16x64)
    f32x4 sacc[4];
#pragma unroll
    for (int nj = 0; nj < 4; ++nj) {
      f32x4 a = {0.f, 0.f, 0.f, 0.f};
      a = mfma16(qf0, *(const bf16x8*)&Kl[(nj * 16 + lr) * 72 + lh * 8], a);
      a = mfma16(qf1, *(const bf16x8*)&Kl[(nj * 16 + lr) * 72 + 32 + lh * 8], a);
      sacc[nj] = a;
    }
    const bool diag = (kt == qt);
    // online softmax: rows (lh*4+r), cols nj*16+lr; row group = 16 consecutive lanes
#pragma unroll
    for (int r = 0; r < 4; ++r) {
      float sv[4];
#pragma unroll
      for (int nj = 0; nj < 4; ++nj) {
        float xv = sacc[nj][r] * 0.125f;
        if (diag && (kt * 64 + nj * 16 + lr) > (qrow_d + r)) xv = -__builtin_inff();
        sv[nj] = xv;
      }
      float pm = fmaxf(fmaxf(sv[0], sv[1]), fmaxf(sv[2], sv[3]));
      pm = fmaxf(pm, __shfl_xor(pm, 1));
      pm = fmaxf(pm, __shfl_xor(pm, 2));
      pm = fmaxf(pm, __shfl_xor(pm, 4));
      pm = fmaxf(pm, __shfl_xor(pm, 8));
      const float mnew = fmaxf(mrun[r], pm);
      const float sc = __expf(mrun[r] - mnew);
      float ps = 0.f;
#pragma unroll
      for (int nj = 0; nj < 4; ++nj) {
        const float pe = __expf(sv[nj] - mnew);
        ps += pe;
        Pl[w][(lh * 4 + r) * 72 + nj * 16 + lr] = tob(pe);
      }
      ps += __shfl_xor(ps, 1);
      ps += __shfl_xor(ps, 2);
      ps += __shfl_xor(ps, 4);
      ps += __shfl_xor(ps, 8);
      lrun[r] = lrun[r] * sc + ps;
      mrun[r] = mnew;
#pragma unroll
      for (int dj = 0; dj < 4; ++dj) acc_o[dj][r] *= sc;
    }
    // O += P V  (A = P from per-wave LDS, B = Vt rows)
#pragma unroll
    for (int dj = 0; dj < 4; ++dj) {
#pragma unroll
      for (int kk = 0; kk < 2; ++kk) {
        bf16x8 pa = *(const bf16x8*)&Pl[w][lr * 72 + kk * 32 + lh * 8];
        bf16x8 vf = *(const bf16x8*)&Vt[(dj * 16 + lr) * 72 + kk * 32 + lh * 8];
        acc_o[dj] = mfma16(pa, vf, acc_o[dj]);
      }
    }
  }
  // epilogue: out [B, T, H*64]
  const int b = bh >> 4, h = bh & 15;
#pragma unroll
  for (int r = 0; r < 4; ++r) {
    const float inv = 1.f / lrun[r];
    const size_t rowb = ((size_t)b * T_ + qrow_d + r) * DEMB_ + h * HD_;
#pragma unroll
    for (int dj = 0; dj < 4; ++dj)
      ob[rowb + dj * 16 + lr] = tob(acc_o[dj][r] * inv);
  }
}

// ---------------- GEMM2: out = attn * w_o^T + b_o (fp32 out) ----------------
__global__ __launch_bounds__(256) void gemm_out_kernel(const bf16_t* __restrict__ A,
                                                       const bf16_t* __restrict__ Bm,
                                                       const float* __restrict__ bo,
                                                       float* __restrict__ out) {
  constexpr int K = DEMB_;
  __shared__ __align__(16) bf16_t As[128 * 32];
  __shared__ __align__(16) bf16_t Bs[128 * 32];
  const int tid = threadIdx.x, w = tid >> 6, l = tid & 63;
  const int lh = l >> 4, lr = l & 15;
  const int m0 = blockIdx.y * 128, n0 = blockIdx.x * 128;
  const int ar0 = (w >> 1) * 64, bc0 = (w & 1) * 64;
  f32x4 acc[4][4] = {};
  for (int k0 = 0; k0 < K; k0 += 32) {
#pragma unroll
    for (int i = 0; i < 2; ++i) {
      const int c = i * 256 + w * 64 + l;
      const int row = c >> 2, col = (c & 3) * 8;
      gload16(A  + (size_t)(m0 + row) * K + k0 + col, (char*)As + (size_t)(i * 256 + w * 64) * 16);
      gload16(Bm + (size_t)(n0 + row) * K + k0 + col, (char*)Bs + (size_t)(i * 256 + w * 64) * 16);
    }
    __syncthreads();
    bf16x8 af[4], bfv[4];
#pragma unroll
    for (int mi = 0; mi < 4; ++mi) af[mi]  = *(const bf16x8*)&As[(ar0 + mi * 16 + lr) * 32 + lh * 8];
#pragma unroll
    for (int ni = 0; ni < 4; ++ni) bfv[ni] = *(const bf16x8*)&Bs[(bc0 + ni * 16 + lr) * 32 + lh * 8];
#pragma unroll
    for (int mi = 0; mi < 4; ++mi)
#pragma unroll
      for (int ni = 0; ni < 4; ++ni)
        acc[mi][ni] = mfma16(af[mi], bfv[ni], acc[mi][ni]);
    __syncthreads();
  }
#pragma unroll
  for (int mi = 0; mi < 4; ++mi) {
#pragma unroll
    for (int r = 0; r < 4; ++r) {
      const int gm = m0 + ar0 + mi * 16 + lh * 4 + r;
#pragma unroll
      for (int ni = 0; ni < 4; ++ni) {
        const int gn = n0 + bc0 + ni * 16 + lr;
        out[(size_t)gm * DEMB_ + gn] = acc[mi][ni][r] + bo[gn];
      }
    }
  }
}

extern "C" void kernel_launch(void* const* d_in, const int* in_sizes, int n_in,
                              void* d_out, int out_size, void* d_ws, size_t ws_size,
                              hipStream_t stream) {
  (void)in_sizes; (void)n_in; (void)out_size; (void)ws_size;
  const float* x     = (const float*)d_in[0];
  const float* w_qkv = (const float*)d_in[1];
  const float* w_o   = (const float*)d_in[2];
  const float* b_o   = (const float*)d_in[3];
  float* out = (float*)d_out;

  char* p = (char*)d_ws;
  bf16_t* xb    = (bf16_t*)p; p += (size_t)M_ * DIN_ * 2;       // 16 MB (reused as attnb)
  bf16_t* wqkvb = (bf16_t*)p; p += (size_t)NQKV_ * DIN_ * 2;    // 6 MB
  bf16_t* wob   = (bf16_t*)p; p += (size_t)DEMB_ * DEMB_ * 2;   // 2 MB
  bf16_t* qbuf  = (bf16_t*)p; p += (size_t)B_ * H_ * T_ * HD_ * 2;
  bf16_t* kbuf  = (bf16_t*)p; p += (size_t)B_ * H_ * T_ * HD_ * 2;
  bf16_t* vbuf  = (bf16_t*)p; p += (size_t)B_ * H_ * T_ * HD_ * 2;
  bf16_t* attnb = xb;  // x no longer needed after GEMM1

  cast_kernel<<<(M_ * DIN_) / 1024, 256, 0, stream>>>(x, xb);
  cast_kernel<<<(NQKV_ * DIN_) / 1024, 256, 0, stream>>>(w_qkv, wqkvb);
  cast_kernel<<<(DEMB_ * DEMB_) / 1024, 256, 0, stream>>>(w_o, wob);
  gemm_qkv_kernel<<<dim3(NQKV_ / 128, M_ / 128), 256, 0, stream>>>(xb, wqkvb, qbuf, kbuf, vbuf);
  attn_kernel<<<dim3(T_ / 64, B_ * H_), 256, 0, stream>>>(qbuf, kbuf, vbuf, attnb);
  gemm_out_kernel<<<dim3(DEMB_ / 128, M_ / 128), 256, 0, stream>>>(attnb, wob, b_o, out);
}

// Round 6
// 355.677 us; speedup vs baseline: 1.2232x; 1.2232x over previous
//
#include <hip/hip_runtime.h>
#include <hip/hip_bf16.h>
#include <cstdint>
#include <cstddef>

#define B_    4
#define T_    2048
#define DIN_  1024
#define DEMB_ 1024
#define H_    16
#define HD_   64
#define M_    8192        // B_*T_
#define NQKV_ 3072        // 3*DEMB_

typedef __bf16 bf16_t;
typedef __bf16 bf16x8 __attribute__((ext_vector_type(8)));
typedef __bf16 bf16x4 __attribute__((ext_vector_type(4)));
typedef float  f32x4  __attribute__((ext_vector_type(4)));

__device__ __forceinline__ bf16_t tob(float f) {
  __hip_bfloat16 h = __float2bfloat16(f);
  return __builtin_bit_cast(bf16_t, h);
}

__device__ __forceinline__ f32x4 mfma16(bf16x8 a, bf16x8 b, f32x4 c) {
  return __builtin_amdgcn_mfma_f32_16x16x32_bf16(a, b, c, 0, 0, 0);
}

__device__ __forceinline__ void gload16(const void* g, void* l) {
  __builtin_amdgcn_global_load_lds((const __attribute__((address_space(1))) void*)g,
                                   (__attribute__((address_space(3))) void*)l, 16, 0, 0);
}

// ---------------- fp32 -> bf16 cast (4 elems/thread) ----------------
__global__ __launch_bounds__(256) void cast_kernel(const float* __restrict__ in,
                                                   bf16_t* __restrict__ out) {
  size_t i = (size_t)blockIdx.x * 256 + threadIdx.x;
  float4 v = ((const float4*)in)[i];
  bf16x4 o;
  o[0] = tob(v.x); o[1] = tob(v.y); o[2] = tob(v.z); o[3] = tob(v.w);
  ((bf16x4*)out)[i] = o;
}

// ---------------- GEMM1: qkv = x * w_qkv^T, scatter to Q/K (row) + V^T (col) ----------------
// Q,K dest: [B,H,T,64].  V dest: [B,H,64,T]  (transposed at the source — no
// separate transpose pass; within a wave the (lh,r) stores per (ni,lr) cover
// 32B-contiguous t-runs of one d-row, so L2 assembles sectors).
__global__ __launch_bounds__(256) void gemm_qkv_kernel(const bf16_t* __restrict__ A,
                                                       const bf16_t* __restrict__ Bm,
                                                       bf16_t* __restrict__ qb,
                                                       bf16_t* __restrict__ kb,
                                                       bf16_t* __restrict__ vbT) {
  constexpr int K = DIN_;
  __shared__ __align__(16) bf16_t As[128 * 32];
  __shared__ __align__(16) bf16_t Bs[128 * 32];
  const int tid = threadIdx.x, w = tid >> 6, l = tid & 63;
  const int lh = l >> 4, lr = l & 15;
  const int m0 = blockIdx.y * 128, n0 = blockIdx.x * 128;
  const int ar0 = (w >> 1) * 64, bc0 = (w & 1) * 64;
  f32x4 acc[4][4] = {};
  for (int k0 = 0; k0 < K; k0 += 32) {
#pragma unroll
    for (int i = 0; i < 2; ++i) {
      const int c = i * 256 + w * 64 + l;
      const int row = c >> 2, col = (c & 3) * 8;
      gload16(A  + (size_t)(m0 + row) * K + k0 + col, (char*)As + (size_t)(i * 256 + w * 64) * 16);
      gload16(Bm + (size_t)(n0 + row) * K + k0 + col, (char*)Bs + (size_t)(i * 256 + w * 64) * 16);
    }
    __syncthreads();
    bf16x8 af[4], bfv[4];
#pragma unroll
    for (int mi = 0; mi < 4; ++mi) af[mi]  = *(const bf16x8*)&As[(ar0 + mi * 16 + lr) * 32 + lh * 8];
#pragma unroll
    for (int ni = 0; ni < 4; ++ni) bfv[ni] = *(const bf16x8*)&Bs[(bc0 + ni * 16 + lr) * 32 + lh * 8];
#pragma unroll
    for (int mi = 0; mi < 4; ++mi)
#pragma unroll
      for (int ni = 0; ni < 4; ++ni)
        acc[mi][ni] = mfma16(af[mi], bfv[ni], acc[mi][ni]);
    __syncthreads();
  }
#pragma unroll
  for (int mi = 0; mi < 4; ++mi) {
#pragma unroll
    for (int r = 0; r < 4; ++r) {
      const int gm = m0 + ar0 + mi * 16 + lh * 4 + r;
      const int bb = gm >> 11, t = gm & (T_ - 1);
#pragma unroll
      for (int ni = 0; ni < 4; ++ni) {
        const int gn = n0 + bc0 + ni * 16 + lr;
        const int h = gn / 192, s = gn - h * 192;
        const size_t bhb = (size_t)bb * H_ + h;
        const bf16_t bv = tob(acc[mi][ni][r]);
        if (s < 64)       qb[(bhb * T_ + t) * HD_ + s] = bv;
        else if (s < 128) kb[(bhb * T_ + t) * HD_ + s - 64] = bv;
        else              vbT[(bhb * HD_ + (s - 128)) * T_ + t] = bv;   // V^T
      }
    }
  }
}

// ---------------- flash attention: round-1 core, V staged from V^T (vector copies) ----------------
__global__ __launch_bounds__(256) void attn_kernel(const bf16_t* __restrict__ qb,
                                                   const bf16_t* __restrict__ kb,
                                                   const bf16_t* __restrict__ vtg,
                                                   bf16_t* __restrict__ ob) {
  __shared__ __align__(16) bf16_t Kl[64 * 72];      // [kv][d] pad 72
  __shared__ __align__(16) bf16_t Vt[64 * 72];      // [d][kv] pad 72
  __shared__ __align__(16) bf16_t Pl[4][16 * 72];   // per-wave P tile
  const int qt = blockIdx.x, bh = blockIdx.y;
  const int tid = threadIdx.x, w = tid >> 6, l = tid & 63;
  const int lh = l >> 4, lr = l & 15;
  const size_t base = (size_t)bh * T_ * HD_;
  const bf16_t* Qg  = qb  + base;
  const bf16_t* Kg  = kb  + base;
  const bf16_t* Vtg = vtg + base;                   // [64][T_] for this (b,h)
  const int qrow_a = qt * 64 + w * 16 + lr;         // A-frag row
  bf16x8 qf0 = *(const bf16x8*)&Qg[(size_t)qrow_a * HD_ + lh * 8];
  bf16x8 qf1 = *(const bf16x8*)&Qg[(size_t)qrow_a * HD_ + 32 + lh * 8];
  const int qrow_d = qt * 64 + w * 16 + lh * 4;     // D-layout row base
  f32x4 acc_o[4] = {};
  float mrun[4], lrun[4];
#pragma unroll
  for (int r = 0; r < 4; ++r) { mrun[r] = -__builtin_inff(); lrun[r] = 0.f; }

  for (int kt = 0; kt <= qt; ++kt) {
    __syncthreads();
    // stage K tile [kv][d] and V^T tile [d][kv] — both pure bf16x8 copies
#pragma unroll
    for (int i = 0; i < 2; ++i) {
      const int c = i * 256 + tid;
      const int row = c >> 3, col = (c & 7) * 8;
      *(bf16x8*)&Kl[row * 72 + col] = *(const bf16x8*)&Kg[(size_t)(kt * 64 + row) * HD_ + col];
      *(bf16x8*)&Vt[row * 72 + col] = *(const bf16x8*)&Vtg[(size_t)row * T_ + kt * 64 + col];
    }
    __syncthreads();

    // S = Q K^T  (per-wave 16x64)
    f32x4 sacc[4];
#pragma unroll
    for (int nj = 0; nj < 4; ++nj) {
      f32x4 a = {0.f, 0.f, 0.f, 0.f};
      a = mfma16(qf0, *(const bf16x8*)&Kl[(nj * 16 + lr) * 72 + lh * 8], a);
      a = mfma16(qf1, *(const bf16x8*)&Kl[(nj * 16 + lr) * 72 + 32 + lh * 8], a);
      sacc[nj] = a;
    }
    const bool diag = (kt == qt);
    // online softmax: rows (lh*4+r), cols nj*16+lr; row group = 16 consecutive lanes
#pragma unroll
    for (int r = 0; r < 4; ++r) {
      float sv[4];
#pragma unroll
      for (int nj = 0; nj < 4; ++nj) {
        float xv = sacc[nj][r] * 0.125f;
        if (diag && (kt * 64 + nj * 16 + lr) > (qrow_d + r)) xv = -__builtin_inff();
        sv[nj] = xv;
      }
      float pm = fmaxf(fmaxf(sv[0], sv[1]), fmaxf(sv[2], sv[3]));
      pm = fmaxf(pm, __shfl_xor(pm, 1));
      pm = fmaxf(pm, __shfl_xor(pm, 2));
      pm = fmaxf(pm, __shfl_xor(pm, 4));
      pm = fmaxf(pm, __shfl_xor(pm, 8));
      const float mnew = fmaxf(mrun[r], pm);
      const float sc = __expf(mrun[r] - mnew);
      float ps = 0.f;
#pragma unroll
      for (int nj = 0; nj < 4; ++nj) {
        const float pe = __expf(sv[nj] - mnew);
        ps += pe;
        Pl[w][(lh * 4 + r) * 72 + nj * 16 + lr] = tob(pe);
      }
      ps += __shfl_xor(ps, 1);
      ps += __shfl_xor(ps, 2);
      ps += __shfl_xor(ps, 4);
      ps += __shfl_xor(ps, 8);
      lrun[r] = lrun[r] * sc + ps;
      mrun[r] = mnew;
#pragma unroll
      for (int dj = 0; dj < 4; ++dj) acc_o[dj][r] *= sc;
    }
    // O += P V  (A = P from per-wave LDS, B = Vt rows)
#pragma unroll
    for (int dj = 0; dj < 4; ++dj) {
#pragma unroll
      for (int kk = 0; kk < 2; ++kk) {
        bf16x8 pa = *(const bf16x8*)&Pl[w][lr * 72 + kk * 32 + lh * 8];
        bf16x8 vf = *(const bf16x8*)&Vt[(dj * 16 + lr) * 72 + kk * 32 + lh * 8];
        acc_o[dj] = mfma16(pa, vf, acc_o[dj]);
      }
    }
  }
  // epilogue: out [B, T, H*64]
  const int b = bh >> 4, h = bh & 15;
#pragma unroll
  for (int r = 0; r < 4; ++r) {
    const float inv = 1.f / lrun[r];
    const size_t rowb = ((size_t)b * T_ + qrow_d + r) * DEMB_ + h * HD_;
#pragma unroll
    for (int dj = 0; dj < 4; ++dj)
      ob[rowb + dj * 16 + lr] = tob(acc_o[dj][r] * inv);
  }
}

// ---------------- GEMM2: out = attn * w_o^T + b_o (fp32 out) ----------------
__global__ __launch_bounds__(256) void gemm_out_kernel(const bf16_t* __restrict__ A,
                                                       const bf16_t* __restrict__ Bm,
                                                       const float* __restrict__ bo,
                                                       float* __restrict__ out) {
  constexpr int K = DEMB_;
  __shared__ __align__(16) bf16_t As[128 * 32];
  __shared__ __align__(16) bf16_t Bs[128 * 32];
  const int tid = threadIdx.x, w = tid >> 6, l = tid & 63;
  const int lh = l >> 4, lr = l & 15;
  const int m0 = blockIdx.y * 128, n0 = blockIdx.x * 128;
  const int ar0 = (w >> 1) * 64, bc0 = (w & 1) * 64;
  f32x4 acc[4][4] = {};
  for (int k0 = 0; k0 < K; k0 += 32) {
#pragma unroll
    for (int i = 0; i < 2; ++i) {
      const int c = i * 256 + w * 64 + l;
      const int row = c >> 2, col = (c & 3) * 8;
      gload16(A  + (size_t)(m0 + row) * K + k0 + col, (char*)As + (size_t)(i * 256 + w * 64) * 16);
      gload16(Bm + (size_t)(n0 + row) * K + k0 + col, (char*)Bs + (size_t)(i * 256 + w * 64) * 16);
    }
    __syncthreads();
    bf16x8 af[4], bfv[4];
#pragma unroll
    for (int mi = 0; mi < 4; ++mi) af[mi]  = *(const bf16x8*)&As[(ar0 + mi * 16 + lr) * 32 + lh * 8];
#pragma unroll
    for (int ni = 0; ni < 4; ++ni) bfv[ni] = *(const bf16x8*)&Bs[(bc0 + ni * 16 + lr) * 32 + lh * 8];
#pragma unroll
    for (int mi = 0; mi < 4; ++mi)
#pragma unroll
      for (int ni = 0; ni < 4; ++ni)
        acc[mi][ni] = mfma16(af[mi], bfv[ni], acc[mi][ni]);
    __syncthreads();
  }
#pragma unroll
  for (int mi = 0; mi < 4; ++mi) {
#pragma unroll
    for (int r = 0; r < 4; ++r) {
      const int gm = m0 + ar0 + mi * 16 + lh * 4 + r;
#pragma unroll
      for (int ni = 0; ni < 4; ++ni) {
        const int gn = n0 + bc0 + ni * 16 + lr;
        out[(size_t)gm * DEMB_ + gn] = acc[mi][ni][r] + bo[gn];
      }
    }
  }
}

extern "C" void kernel_launch(void* const* d_in, const int* in_sizes, int n_in,
                              void* d_out, int out_size, void* d_ws, size_t ws_size,
                              hipStream_t stream) {
  (void)in_sizes; (void)n_in; (void)out_size; (void)ws_size;
  const float* x     = (const float*)d_in[0];
  const float* w_qkv = (const float*)d_in[1];
  const float* w_o   = (const float*)d_in[2];
  const float* b_o   = (const float*)d_in[3];
  float* out = (float*)d_out;

  // Round-1-proven 75.5 MB workspace layout; vbuf now holds V^T [B,H,64,T].
  char* p = (char*)d_ws;
  bf16_t* xb    = (bf16_t*)p; p += (size_t)M_ * DIN_ * 2;
  bf16_t* wqkvb = (bf16_t*)p; p += (size_t)NQKV_ * DIN_ * 2;
  bf16_t* wob   = (bf16_t*)p; p += (size_t)DEMB_ * DEMB_ * 2;
  bf16_t* qbuf  = (bf16_t*)p; p += (size_t)B_ * H_ * T_ * HD_ * 2;
  bf16_t* kbuf  = (bf16_t*)p; p += (size_t)B_ * H_ * T_ * HD_ * 2;
  bf16_t* vbuf  = (bf16_t*)p; p += (size_t)B_ * H_ * T_ * HD_ * 2;
  bf16_t* attnb = xb;    // x dead after gemm1 (round-1 aliasing)

  cast_kernel<<<(M_ * DIN_) / 1024, 256, 0, stream>>>(x, xb);
  cast_kernel<<<(NQKV_ * DIN_) / 1024, 256, 0, stream>>>(w_qkv, wqkvb);
  cast_kernel<<<(DEMB_ * DEMB_) / 1024, 256, 0, stream>>>(w_o, wob);
  gemm_qkv_kernel<<<dim3(NQKV_ / 128, M_ / 128), 256, 0, stream>>>(xb, wqkvb, qbuf, kbuf, vbuf);
  attn_kernel<<<dim3(T_ / 64, B_ * H_), 256, 0, stream>>>(qbuf, kbuf, vbuf, attnb);
  gemm_out_kernel<<<dim3(DEMB_ / 128, M_ / 128), 256, 0, stream>>>(attnb, wob, b_o, out);
}

// Round 7
// 200.325 us; speedup vs baseline: 2.1718x; 1.7755x over previous
//
#include <hip/hip_runtime.h>
#include <hip/hip_bf16.h>
#include <cstdint>
#include <cstddef>

#define B_    4
#define T_    2048
#define DIN_  1024
#define DEMB_ 1024
#define H_    16
#define HD_   64
#define M_    8192        // B_*T_
#define NQKV_ 3072        // 3*DEMB_

// Q pre-scale: 1/sqrt(HD) * log2(e)  (softmax done in exp2 domain)
#define QSCALE 0.18033688011112042f

typedef __bf16 bf16_t;
typedef __bf16 bf16x8 __attribute__((ext_vector_type(8)));
typedef __bf16 bf16x4 __attribute__((ext_vector_type(4)));
typedef float  f32x4  __attribute__((ext_vector_type(4)));
typedef float  f32x16 __attribute__((ext_vector_type(16)));
typedef unsigned int u32x4 __attribute__((ext_vector_type(4)));

__device__ __forceinline__ bf16_t tob(float f) {
  __hip_bfloat16 h = __float2bfloat16(f);
  return __builtin_bit_cast(bf16_t, h);
}

__device__ __forceinline__ f32x4 mfma16(bf16x8 a, bf16x8 b, f32x4 c) {
  return __builtin_amdgcn_mfma_f32_16x16x32_bf16(a, b, c, 0, 0, 0);
}
__device__ __forceinline__ f32x16 mfma32(bf16x8 a, bf16x8 b, f32x16 c) {
  return __builtin_amdgcn_mfma_f32_32x32x16_bf16(a, b, c, 0, 0, 0);
}

__device__ __forceinline__ float fexp2(float x) {
#if __has_builtin(__builtin_amdgcn_exp2f)
  return __builtin_amdgcn_exp2f(x);
#else
  return exp2f(x);
#endif
}

__device__ __forceinline__ unsigned pk2(float lo, float hi) {
  unsigned a = (unsigned)__builtin_bit_cast(unsigned short, tob(lo));
  unsigned b = (unsigned)__builtin_bit_cast(unsigned short, tob(hi));
  return a | (b << 16);
}

__device__ __forceinline__ void gload16(const void* g, void* l) {
  __builtin_amdgcn_global_load_lds((const __attribute__((address_space(1))) void*)g,
                                   (__attribute__((address_space(3))) void*)l, 16, 0, 0);
}

// ---------------- fp32 -> bf16 cast (4 elems/thread) ----------------
__global__ __launch_bounds__(256) void cast_kernel(const float* __restrict__ in,
                                                   bf16_t* __restrict__ out) {
  size_t i = (size_t)blockIdx.x * 256 + threadIdx.x;
  float4 v = ((const float4*)in)[i];
  bf16x4 o;
  o[0] = tob(v.x); o[1] = tob(v.y); o[2] = tob(v.z); o[3] = tob(v.w);
  ((bf16x4*)out)[i] = o;
}

// ---------------- GEMM1: qkv = x * w_qkv^T, scatter to Q(scaled)/K (row) + V^T (col) ----------------
__global__ __launch_bounds__(256) void gemm_qkv_kernel(const bf16_t* __restrict__ A,
                                                       const bf16_t* __restrict__ Bm,
                                                       bf16_t* __restrict__ qb,
                                                       bf16_t* __restrict__ kb,
                                                       bf16_t* __restrict__ vbT) {
  constexpr int K = DIN_;
  __shared__ __align__(16) bf16_t As[128 * 32];
  __shared__ __align__(16) bf16_t Bs[128 * 32];
  const int tid = threadIdx.x, w = tid >> 6, l = tid & 63;
  const int lh = l >> 4, lr = l & 15;
  const int m0 = blockIdx.y * 128, n0 = blockIdx.x * 128;
  const int ar0 = (w >> 1) * 64, bc0 = (w & 1) * 64;
  f32x4 acc[4][4] = {};
  for (int k0 = 0; k0 < K; k0 += 32) {
#pragma unroll
    for (int i = 0; i < 2; ++i) {
      const int c = i * 256 + w * 64 + l;
      const int row = c >> 2, col = (c & 3) * 8;
      gload16(A  + (size_t)(m0 + row) * K + k0 + col, (char*)As + (size_t)(i * 256 + w * 64) * 16);
      gload16(Bm + (size_t)(n0 + row) * K + k0 + col, (char*)Bs + (size_t)(i * 256 + w * 64) * 16);
    }
    __syncthreads();
    bf16x8 af[4], bfv[4];
#pragma unroll
    for (int mi = 0; mi < 4; ++mi) af[mi]  = *(const bf16x8*)&As[(ar0 + mi * 16 + lr) * 32 + lh * 8];
#pragma unroll
    for (int ni = 0; ni < 4; ++ni) bfv[ni] = *(const bf16x8*)&Bs[(bc0 + ni * 16 + lr) * 32 + lh * 8];
#pragma unroll
    for (int mi = 0; mi < 4; ++mi)
#pragma unroll
      for (int ni = 0; ni < 4; ++ni)
        acc[mi][ni] = mfma16(af[mi], bfv[ni], acc[mi][ni]);
    __syncthreads();
  }
#pragma unroll
  for (int mi = 0; mi < 4; ++mi) {
#pragma unroll
    for (int r = 0; r < 4; ++r) {
      const int gm = m0 + ar0 + mi * 16 + lh * 4 + r;
      const int bb = gm >> 11, t = gm & (T_ - 1);
#pragma unroll
      for (int ni = 0; ni < 4; ++ni) {
        const int gn = n0 + bc0 + ni * 16 + lr;
        const int h = gn / 192, s = gn - h * 192;
        const size_t bhb = (size_t)bb * H_ + h;
        const float val = acc[mi][ni][r];
        if (s < 64)       qb[(bhb * T_ + t) * HD_ + s] = tob(val * QSCALE);
        else if (s < 128) kb[(bhb * T_ + t) * HD_ + s - 64] = tob(val);
        else              vbT[(bhb * HD_ + (s - 128)) * T_ + t] = tob(val);   // V^T
      }
    }
  }
}

// ---------------- flash attention: swapped-QK 32x32, in-register softmax ----------------
// 8 waves x 32 q-rows = QBLK 256. KVBLK = 64, double-buffered LDS.
// Block x in [0,4): handles q-tiles {x, 7-x} (causal load balance). bh grouped per XCD.
__global__ __launch_bounds__(512, 2) void attn2_kernel(const bf16_t* __restrict__ qg,
                                                       const bf16_t* __restrict__ kg,
                                                       const bf16_t* __restrict__ vtg,
                                                       bf16_t* __restrict__ ob) {
  __shared__ __align__(16) bf16_t Kl[2][64 * 72];   // [kv][d], pad 72
  __shared__ __align__(16) bf16_t Vl[2][64 * 72];   // [d][kv], pad 72
  const int id = blockIdx.x;
  const int x  = (id >> 3) & 3;
  const int bh = (id & 7) | ((id >> 5) << 3);       // same-bh blocks share an XCD
  const int tid = threadIdx.x, w = tid >> 6, l = tid & 63;
  const int q5 = l & 31, hi = l >> 5, hi8 = hi * 8;
  const int srow = tid >> 3, scol = (tid & 7) * 8;  // staging: 64 rows x 64 cols
  const bf16_t* Qg  = qg  + (size_t)bh * T_ * HD_;
  const bf16_t* Kg  = kg  + (size_t)bh * T_ * HD_;
  const bf16_t* Vtg = vtg + (size_t)bh * HD_ * T_;

  for (int ph = 0; ph < 2; ++ph) {
    const int qt = ph ? (7 - x) : x;
    const int qb = qt * 256 + w * 32;
    const int ktmax = 4 * qt + 4;
    const int myKt  = qb >> 6;
    const int thrD  = qb + q5 - myKt * 64 - 4 * hi;  // mask if kvc+32*t32 > thrD on diag tile

    bf16x8 bq[4];
#pragma unroll
    for (int s = 0; s < 4; ++s)
      bq[s] = *(const bf16x8*)&Qg[(size_t)(qb + q5) * HD_ + s * 16 + hi8];

    f32x16 o0 = {}, o1 = {};
    float mrun = -1e30f, lrun = 0.f;

    // prologue: stage tile 0
    {
      bf16x8 gk = *(const bf16x8*)&Kg[(size_t)srow * HD_ + scol];
      bf16x8 gv = *(const bf16x8*)&Vtg[(size_t)srow * T_ + scol];
      *(bf16x8*)&Kl[0][srow * 72 + scol] = gk;
      *(bf16x8*)&Vl[0][srow * 72 + scol] = gv;
    }
    __syncthreads();
    int cur = 0;

    for (int kt = 0; kt < ktmax; ++kt) {
      const bool more = (kt + 1 < ktmax);
      bf16x8 nk, nv;
      if (more) {  // issue next-tile loads early (hide HBM under compute)
        nk = *(const bf16x8*)&Kg[(size_t)((kt + 1) * 64 + srow) * HD_ + scol];
        nv = *(const bf16x8*)&Vtg[(size_t)srow * T_ + (kt + 1) * 64 + scol];
      }
      if (kt <= myKt) {
        // ---- QK^T (swapped): sA/sB = S^T for kv 0..31 / 32..63, col = q ----
        f32x16 sA = {}, sB = {};
#pragma unroll
        for (int s = 0; s < 4; ++s) {
          bf16x8 a0 = *(const bf16x8*)&Kl[cur][(q5)      * 72 + s * 16 + hi8];
          bf16x8 a1 = *(const bf16x8*)&Kl[cur][(q5 + 32) * 72 + s * 16 + hi8];
          sA = mfma32(a0, bq[s], sA);
          sB = mfma32(a1, bq[s], sB);
        }
        // ---- causal mask (diag tile only) ----
        if (kt == myKt) {
#pragma unroll
          for (int r = 0; r < 16; ++r) {
            const int kvc = (r & 3) + 8 * (r >> 2);
            sA[r] = (kvc      > thrD) ? -1e30f : sA[r];
            sB[r] = (kvc + 32 > thrD) ? -1e30f : sB[r];
          }
        }
        // ---- in-register online softmax (exp2 domain) ----
        float mA = -1e30f, mB = -1e30f, mC = -1e30f, mD = -1e30f;
#pragma unroll
        for (int r = 0; r < 16; r += 4) {
          mA = fmaxf(mA, fmaxf(sA[r],     sB[r]));
          mB = fmaxf(mB, fmaxf(sA[r + 1], sB[r + 1]));
          mC = fmaxf(mC, fmaxf(sA[r + 2], sB[r + 2]));
          mD = fmaxf(mD, fmaxf(sA[r + 3], sB[r + 3]));
        }
        float mt = fmaxf(fmaxf(mA, mB), fmaxf(mC, mD));
        mt = fmaxf(mt, __shfl_xor(mt, 32));
        if (!__all(mt <= mrun + 8.f)) {    // defer-max (T13)
          const float mnew = fmaxf(mrun, mt);
          const float sc = fexp2(mrun - mnew);
          lrun *= sc;
#pragma unroll
          for (int r = 0; r < 16; ++r) { o0[r] *= sc; o1[r] *= sc; }
          mrun = mnew;
        }
        float l0 = 0.f, l1 = 0.f, l2 = 0.f, l3 = 0.f;
#pragma unroll
        for (int r = 0; r < 16; r += 4) {
          sA[r]     = fexp2(sA[r]     - mrun); sB[r]     = fexp2(sB[r]     - mrun);
          sA[r + 1] = fexp2(sA[r + 1] - mrun); sB[r + 1] = fexp2(sB[r + 1] - mrun);
          sA[r + 2] = fexp2(sA[r + 2] - mrun); sB[r + 2] = fexp2(sB[r + 2] - mrun);
          sA[r + 3] = fexp2(sA[r + 3] - mrun); sB[r + 3] = fexp2(sB[r + 3] - mrun);
          l0 += sA[r]     + sB[r];
          l1 += sA[r + 1] + sB[r + 1];
          l2 += sA[r + 2] + sB[r + 2];
          l3 += sA[r + 3] + sB[r + 3];
        }
        lrun += (l0 + l1) + (l2 + l3);
        // ---- P -> bf16 B-frags (pack + lane32 exchange) and PV ----
#pragma unroll
        for (int t32 = 0; t32 < 2; ++t32) {
          const f32x16& p = t32 ? sB : sA;
#pragma unroll
          for (int s2 = 0; s2 < 2; ++s2) {
            const unsigned w0 = pk2(p[8 * s2 + 0], p[8 * s2 + 1]);
            const unsigned w1 = pk2(p[8 * s2 + 2], p[8 * s2 + 3]);
            const unsigned w2 = pk2(p[8 * s2 + 4], p[8 * s2 + 5]);
            const unsigned w3 = pk2(p[8 * s2 + 6], p[8 * s2 + 7]);
            const unsigned pw0 = __shfl_xor(w0, 32);
            const unsigned pw1 = __shfl_xor(w1, 32);
            const unsigned pw2 = __shfl_xor(w2, 32);
            const unsigned pw3 = __shfl_xor(w3, 32);
            u32x4 fw;
            fw.x = hi ? pw2 : w0;
            fw.y = hi ? pw3 : w1;
            fw.z = hi ? w2  : pw0;
            fw.w = hi ? w3  : pw1;
            const bf16x8 pb = __builtin_bit_cast(bf16x8, fw);
            const int kvo = t32 * 32 + s2 * 16 + hi8;
            bf16x8 av0 = *(const bf16x8*)&Vl[cur][(q5)      * 72 + kvo];
            bf16x8 av1 = *(const bf16x8*)&Vl[cur][(q5 + 32) * 72 + kvo];
            o0 = mfma32(av0, pb, o0);
            o1 = mfma32(av1, pb, o1);
          }
        }
      }
      if (more) {
        *(bf16x8*)&Kl[cur ^ 1][srow * 72 + scol] = nk;
        *(bf16x8*)&Vl[cur ^ 1][srow * 72 + scol] = nv;
      }
      __syncthreads();
      cur ^= 1;
    }

    // ---- epilogue: combine l across lane pairs, normalize, store O ----
    const float ltot = lrun + __shfl_xor(lrun, 32);
    const float inv = 1.f / ltot;
    const size_t rowb = ((size_t)(bh >> 4) * T_ + qb + q5) * DEMB_ + (bh & 15) * HD_;
#pragma unroll
    for (int g = 0; g < 4; ++g) {
      bf16x4 st0, st1;
#pragma unroll
      for (int j = 0; j < 4; ++j) {
        st0[j] = tob(o0[4 * g + j] * inv);
        st1[j] = tob(o1[4 * g + j] * inv);
      }
      *(bf16x4*)&ob[rowb + 8 * g + 4 * hi]      = st0;
      *(bf16x4*)&ob[rowb + 8 * g + 4 * hi + 32] = st1;
    }
  }
}

// ---------------- GEMM2: out = attn * w_o^T + b_o (fp32 out) ----------------
__global__ __launch_bounds__(256) void gemm_out_kernel(const bf16_t* __restrict__ A,
                                                       const bf16_t* __restrict__ Bm,
                                                       const float* __restrict__ bo,
                                                       float* __restrict__ out) {
  constexpr int K = DEMB_;
  __shared__ __align__(16) bf16_t As[128 * 32];
  __shared__ __align__(16) bf16_t Bs[128 * 32];
  const int tid = threadIdx.x, w = tid >> 6, l = tid & 63;
  const int lh = l >> 4, lr = l & 15;
  const int m0 = blockIdx.y * 128, n0 = blockIdx.x * 128;
  const int ar0 = (w >> 1) * 64, bc0 = (w & 1) * 64;
  f32x4 acc[4][4] = {};
  for (int k0 = 0; k0 < K; k0 += 32) {
#pragma unroll
    for (int i = 0; i < 2; ++i) {
      const int c = i * 256 + w * 64 + l;
      const int row = c >> 2, col = (c & 3) * 8;
      gload16(A  + (size_t)(m0 + row) * K + k0 + col, (char*)As + (size_t)(i * 256 + w * 64) * 16);
      gload16(Bm + (size_t)(n0 + row) * K + k0 + col, (char*)Bs + (size_t)(i * 256 + w * 64) * 16);
    }
    __syncthreads();
    bf16x8 af[4], bfv[4];
#pragma unroll
    for (int mi = 0; mi < 4; ++mi) af[mi]  = *(const bf16x8*)&As[(ar0 + mi * 16 + lr) * 32 + lh * 8];
#pragma unroll
    for (int ni = 0; ni < 4; ++ni) bfv[ni] = *(const bf16x8*)&Bs[(bc0 + ni * 16 + lr) * 32 + lh * 8];
#pragma unroll
    for (int mi = 0; mi < 4; ++mi)
#pragma unroll
      for (int ni = 0; ni < 4; ++ni)
        acc[mi][ni] = mfma16(af[mi], bfv[ni], acc[mi][ni]);
    __syncthreads();
  }
#pragma unroll
  for (int mi = 0; mi < 4; ++mi) {
#pragma unroll
    for (int r = 0; r < 4; ++r) {
      const int gm = m0 + ar0 + mi * 16 + lh * 4 + r;
#pragma unroll
      for (int ni = 0; ni < 4; ++ni) {
        const int gn = n0 + bc0 + ni * 16 + lr;
        out[(size_t)gm * DEMB_ + gn] = acc[mi][ni][r] + bo[gn];
      }
    }
  }
}

extern "C" void kernel_launch(void* const* d_in, const int* in_sizes, int n_in,
                              void* d_out, int out_size, void* d_ws, size_t ws_size,
                              hipStream_t stream) {
  (void)in_sizes; (void)n_in; (void)out_size; (void)ws_size;
  const float* x     = (const float*)d_in[0];
  const float* w_qkv = (const float*)d_in[1];
  const float* w_o   = (const float*)d_in[2];
  const float* b_o   = (const float*)d_in[3];
  float* out = (float*)d_out;

  // Round-1-proven 75.5 MB workspace layout; vbuf holds V^T [B,H,64,T].
  char* p = (char*)d_ws;
  bf16_t* xb    = (bf16_t*)p; p += (size_t)M_ * DIN_ * 2;
  bf16_t* wqkvb = (bf16_t*)p; p += (size_t)NQKV_ * DIN_ * 2;
  bf16_t* wob   = (bf16_t*)p; p += (size_t)DEMB_ * DEMB_ * 2;
  bf16_t* qbuf  = (bf16_t*)p; p += (size_t)B_ * H_ * T_ * HD_ * 2;
  bf16_t* kbuf  = (bf16_t*)p; p += (size_t)B_ * H_ * T_ * HD_ * 2;
  bf16_t* vbuf  = (bf16_t*)p; p += (size_t)B_ * H_ * T_ * HD_ * 2;
  bf16_t* attnb = xb;    // x dead after gemm1

  cast_kernel<<<(M_ * DIN_) / 1024, 256, 0, stream>>>(x, xb);
  cast_kernel<<<(NQKV_ * DIN_) / 1024, 256, 0, stream>>>(w_qkv, wqkvb);
  cast_kernel<<<(DEMB_ * DEMB_) / 1024, 256, 0, stream>>>(w_o, wob);
  gemm_qkv_kernel<<<dim3(NQKV_ / 128, M_ / 128), 256, 0, stream>>>(xb, wqkvb, qbuf, kbuf, vbuf);
  attn2_kernel<<<256, 512, 0, stream>>>(qbuf, kbuf, vbuf, attnb);
  gemm_out_kernel<<<dim3(DEMB_ / 128, M_ / 128), 256, 0, stream>>>(attnb, wob, b_o, out);
}

// Round 8
// 197.265 us; speedup vs baseline: 2.2055x; 1.0155x over previous
//
#include <hip/hip_runtime.h>
#include <hip/hip_bf16.h>
#include <cstdint>
#include <cstddef>

#define B_    4
#define T_    2048
#define DIN_  1024
#define DEMB_ 1024
#define H_    16
#define HD_   64
#define M_    8192        // B_*T_
#define NQKV_ 3072        // 3*DEMB_

// Q pre-scale: 1/sqrt(HD) * log2(e)  (softmax done in exp2 domain)
#define QSCALE 0.18033688011112042f

typedef __bf16 bf16_t;
typedef __bf16 bf16x8 __attribute__((ext_vector_type(8)));
typedef __bf16 bf16x4 __attribute__((ext_vector_type(4)));
typedef float  f32x4  __attribute__((ext_vector_type(4)));
typedef float  f32x16 __attribute__((ext_vector_type(16)));
typedef unsigned int u32x4 __attribute__((ext_vector_type(4)));

__device__ __forceinline__ bf16_t tob(float f) {
  __hip_bfloat16 h = __float2bfloat16(f);
  return __builtin_bit_cast(bf16_t, h);
}

__device__ __forceinline__ f32x4 mfma16(bf16x8 a, bf16x8 b, f32x4 c) {
  return __builtin_amdgcn_mfma_f32_16x16x32_bf16(a, b, c, 0, 0, 0);
}
__device__ __forceinline__ f32x16 mfma32(bf16x8 a, bf16x8 b, f32x16 c) {
  return __builtin_amdgcn_mfma_f32_32x32x16_bf16(a, b, c, 0, 0, 0);
}

__device__ __forceinline__ float fexp2(float x) {
#if __has_builtin(__builtin_amdgcn_exp2f)
  return __builtin_amdgcn_exp2f(x);
#else
  return exp2f(x);
#endif
}

// packed f32x2 -> bf16x2 (RNE) in one VALU op (T12 primitive; no builtin on gfx950)
__device__ __forceinline__ unsigned pk2(float lo, float hi) {
  unsigned r;
  asm("v_cvt_pk_bf16_f32 %0, %1, %2" : "=v"(r) : "v"(lo), "v"(hi));
  return r;
}

__device__ __forceinline__ void gload16(const void* g, void* l) {
  __builtin_amdgcn_global_load_lds((const __attribute__((address_space(1))) void*)g,
                                   (__attribute__((address_space(3))) void*)l, 16, 0, 0);
}

// ---------------- fp32 -> bf16 cast (4 elems/thread) ----------------
__global__ __launch_bounds__(256) void cast_kernel(const float* __restrict__ in,
                                                   bf16_t* __restrict__ out) {
  size_t i = (size_t)blockIdx.x * 256 + threadIdx.x;
  float4 v = ((const float4*)in)[i];
  bf16x4 o;
  o[0] = tob(v.x); o[1] = tob(v.y); o[2] = tob(v.z); o[3] = tob(v.w);
  ((bf16x4*)out)[i] = o;
}

// ---------------- GEMM1: qkv = x * w_qkv^T, scatter Q(scaled)/K (row) + V^T (col) ----------------
// 2-phase pipelined staging: double-buffered LDS, next tile's global_load_lds
// issued BEFORE current tile's ds_read+MFMA, single barrier per K-step (T3 min).
__global__ __launch_bounds__(256) void gemm_qkv_kernel(const bf16_t* __restrict__ A,
                                                       const bf16_t* __restrict__ Bm,
                                                       bf16_t* __restrict__ qb,
                                                       bf16_t* __restrict__ kb,
                                                       bf16_t* __restrict__ vbT) {
  constexpr int K = DIN_;
  __shared__ __align__(16) bf16_t As[2][128 * 32];
  __shared__ __align__(16) bf16_t Bs[2][128 * 32];
  const int tid = threadIdx.x, w = tid >> 6, l = tid & 63;
  const int lh = l >> 4, lr = l & 15;
  const int m0 = blockIdx.y * 128, n0 = blockIdx.x * 128;
  const int ar0 = (w >> 1) * 64, bc0 = (w & 1) * 64;

  auto stage = [&](int k0, int buf) {
#pragma unroll
    for (int i = 0; i < 2; ++i) {
      const int c = i * 256 + w * 64 + l;
      const int row = c >> 2, col = (c & 3) * 8;
      gload16(A  + (size_t)(m0 + row) * K + k0 + col,
              (char*)&As[buf][0] + (size_t)(i * 256 + w * 64) * 16);
      gload16(Bm + (size_t)(n0 + row) * K + k0 + col,
              (char*)&Bs[buf][0] + (size_t)(i * 256 + w * 64) * 16);
    }
  };

  f32x4 acc[4][4] = {};
  stage(0, 0);
  __syncthreads();
  int cur = 0;
  for (int k0 = 0; k0 < K; k0 += 32) {
    if (k0 + 32 < K) stage(k0 + 32, cur ^ 1);   // issue next tile early
    bf16x8 af[4], bfv[4];
#pragma unroll
    for (int mi = 0; mi < 4; ++mi) af[mi]  = *(const bf16x8*)&As[cur][(ar0 + mi * 16 + lr) * 32 + lh * 8];
#pragma unroll
    for (int ni = 0; ni < 4; ++ni) bfv[ni] = *(const bf16x8*)&Bs[cur][(bc0 + ni * 16 + lr) * 32 + lh * 8];
#pragma unroll
    for (int mi = 0; mi < 4; ++mi)
#pragma unroll
      for (int ni = 0; ni < 4; ++ni)
        acc[mi][ni] = mfma16(af[mi], bfv[ni], acc[mi][ni]);
    __syncthreads();   // drains staged loads (vmcnt) + guards buffer reuse
    cur ^= 1;
  }
#pragma unroll
  for (int mi = 0; mi < 4; ++mi) {
#pragma unroll
    for (int r = 0; r < 4; ++r) {
      const int gm = m0 + ar0 + mi * 16 + lh * 4 + r;
      const int bb = gm >> 11, t = gm & (T_ - 1);
#pragma unroll
      for (int ni = 0; ni < 4; ++ni) {
        const int gn = n0 + bc0 + ni * 16 + lr;
        const int h = gn / 192, s = gn - h * 192;
        const size_t bhb = (size_t)bb * H_ + h;
        const float val = acc[mi][ni][r];
        if (s < 64)       qb[(bhb * T_ + t) * HD_ + s] = tob(val * QSCALE);
        else if (s < 128) kb[(bhb * T_ + t) * HD_ + s - 64] = tob(val);
        else              vbT[(bhb * HD_ + (s - 128)) * T_ + t] = tob(val);   // V^T
      }
    }
  }
}

// ---------------- flash attention: swapped-QK 32x32, in-register softmax ----------------
// 8 waves x 32 q-rows = QBLK 256. KVBLK = 64, double-buffered LDS.
// Block x in [0,4): handles q-tiles {x, 7-x} (causal load balance). bh grouped per XCD.
__global__ __launch_bounds__(512, 2) void attn2_kernel(const bf16_t* __restrict__ qg,
                                                       const bf16_t* __restrict__ kg,
                                                       const bf16_t* __restrict__ vtg,
                                                       bf16_t* __restrict__ ob) {
  __shared__ __align__(16) bf16_t Kl[2][64 * 72];   // [kv][d], pad 72
  __shared__ __align__(16) bf16_t Vl[2][64 * 72];   // [d][kv], pad 72
  const int id = blockIdx.x;
  const int x  = (id >> 3) & 3;
  const int bh = (id & 7) | ((id >> 5) << 3);       // same-bh blocks share an XCD
  const int tid = threadIdx.x, w = tid >> 6, l = tid & 63;
  const int q5 = l & 31, hi = l >> 5, hi8 = hi * 8;
  const int srow = tid >> 3, scol = (tid & 7) * 8;  // staging: 64 rows x 64 cols
  const bf16_t* Qg  = qg  + (size_t)bh * T_ * HD_;
  const bf16_t* Kg  = kg  + (size_t)bh * T_ * HD_;
  const bf16_t* Vtg = vtg + (size_t)bh * HD_ * T_;

  for (int ph = 0; ph < 2; ++ph) {
    const int qt = ph ? (7 - x) : x;
    const int qb = qt * 256 + w * 32;
    const int ktmax = 4 * qt + 4;
    const int myKt  = qb >> 6;
    const int thrD  = qb + q5 - myKt * 64 - 4 * hi;  // mask if kvc+32*t32 > thrD on diag tile

    bf16x8 bq[4];
#pragma unroll
    for (int s = 0; s < 4; ++s)
      bq[s] = *(const bf16x8*)&Qg[(size_t)(qb + q5) * HD_ + s * 16 + hi8];

    f32x16 o0 = {}, o1 = {};
    float mrun = -1e30f, lrun = 0.f;

    // prologue: stage tile 0
    {
      bf16x8 gk = *(const bf16x8*)&Kg[(size_t)srow * HD_ + scol];
      bf16x8 gv = *(const bf16x8*)&Vtg[(size_t)srow * T_ + scol];
      *(bf16x8*)&Kl[0][srow * 72 + scol] = gk;
      *(bf16x8*)&Vl[0][srow * 72 + scol] = gv;
    }
    __syncthreads();
    int cur = 0;

    for (int kt = 0; kt < ktmax; ++kt) {
      const bool more = (kt + 1 < ktmax);
      bf16x8 nk, nv;
      if (more) {  // issue next-tile loads early (hide HBM under compute)
        nk = *(const bf16x8*)&Kg[(size_t)((kt + 1) * 64 + srow) * HD_ + scol];
        nv = *(const bf16x8*)&Vtg[(size_t)srow * T_ + (kt + 1) * 64 + scol];
      }
      if (kt <= myKt) {
        // ---- QK^T (swapped): sA/sB = S^T for kv 0..31 / 32..63, col = q ----
        f32x16 sA = {}, sB = {};
        __builtin_amdgcn_s_setprio(1);
#pragma unroll
        for (int s = 0; s < 4; ++s) {
          bf16x8 a0 = *(const bf16x8*)&Kl[cur][(q5)      * 72 + s * 16 + hi8];
          bf16x8 a1 = *(const bf16x8*)&Kl[cur][(q5 + 32) * 72 + s * 16 + hi8];
          sA = mfma32(a0, bq[s], sA);
          sB = mfma32(a1, bq[s], sB);
        }
        __builtin_amdgcn_s_setprio(0);
        // ---- causal mask (diag tile only) ----
        if (kt == myKt) {
#pragma unroll
          for (int r = 0; r < 16; ++r) {
            const int kvc = (r & 3) + 8 * (r >> 2);
            sA[r] = (kvc      > thrD) ? -1e30f : sA[r];
            sB[r] = (kvc + 32 > thrD) ? -1e30f : sB[r];
          }
        }
        // ---- in-register online softmax (exp2 domain) ----
        float mA = -1e30f, mB = -1e30f, mC = -1e30f, mD = -1e30f;
#pragma unroll
        for (int r = 0; r < 16; r += 4) {
          mA = fmaxf(mA, fmaxf(sA[r],     sB[r]));
          mB = fmaxf(mB, fmaxf(sA[r + 1], sB[r + 1]));
          mC = fmaxf(mC, fmaxf(sA[r + 2], sB[r + 2]));
          mD = fmaxf(mD, fmaxf(sA[r + 3], sB[r + 3]));
        }
        float mt = fmaxf(fmaxf(mA, mB), fmaxf(mC, mD));
        mt = fmaxf(mt, __shfl_xor(mt, 32));
        if (!__all(mt <= mrun + 8.f)) {    // defer-max (T13)
          const float mnew = fmaxf(mrun, mt);
          const float sc = fexp2(mrun - mnew);
          lrun *= sc;
#pragma unroll
          for (int r = 0; r < 16; ++r) { o0[r] *= sc; o1[r] *= sc; }
          mrun = mnew;
        }
        float l0 = 0.f, l1 = 0.f, l2 = 0.f, l3 = 0.f;
#pragma unroll
        for (int r = 0; r < 16; r += 4) {
          sA[r]     = fexp2(sA[r]     - mrun); sB[r]     = fexp2(sB[r]     - mrun);
          sA[r + 1] = fexp2(sA[r + 1] - mrun); sB[r + 1] = fexp2(sB[r + 1] - mrun);
          sA[r + 2] = fexp2(sA[r + 2] - mrun); sB[r + 2] = fexp2(sB[r + 2] - mrun);
          sA[r + 3] = fexp2(sA[r + 3] - mrun); sB[r + 3] = fexp2(sB[r + 3] - mrun);
          l0 += sA[r]     + sB[r];
          l1 += sA[r + 1] + sB[r + 1];
          l2 += sA[r + 2] + sB[r + 2];
          l3 += sA[r + 3] + sB[r + 3];
        }
        lrun += (l0 + l1) + (l2 + l3);
        // ---- P -> bf16 B-frags (cvt_pk + lane32 exchange) and PV ----
#pragma unroll
        for (int t32 = 0; t32 < 2; ++t32) {
          const f32x16& p = t32 ? sB : sA;
#pragma unroll
          for (int s2 = 0; s2 < 2; ++s2) {
            const unsigned w0 = pk2(p[8 * s2 + 0], p[8 * s2 + 1]);
            const unsigned w1 = pk2(p[8 * s2 + 2], p[8 * s2 + 3]);
            const unsigned w2 = pk2(p[8 * s2 + 4], p[8 * s2 + 5]);
            const unsigned w3 = pk2(p[8 * s2 + 6], p[8 * s2 + 7]);
            const unsigned pw0 = __shfl_xor(w0, 32);
            const unsigned pw1 = __shfl_xor(w1, 32);
            const unsigned pw2 = __shfl_xor(w2, 32);
            const unsigned pw3 = __shfl_xor(w3, 32);
            u32x4 fw;
            fw.x = hi ? pw2 : w0;
            fw.y = hi ? pw3 : w1;
            fw.z = hi ? w2  : pw0;
            fw.w = hi ? w3  : pw1;
            const bf16x8 pb = __builtin_bit_cast(bf16x8, fw);
            const int kvo = t32 * 32 + s2 * 16 + hi8;
            bf16x8 av0 = *(const bf16x8*)&Vl[cur][(q5)      * 72 + kvo];
            bf16x8 av1 = *(const bf16x8*)&Vl[cur][(q5 + 32) * 72 + kvo];
            __builtin_amdgcn_s_setprio(1);
            o0 = mfma32(av0, pb, o0);
            o1 = mfma32(av1, pb, o1);
            __builtin_amdgcn_s_setprio(0);
          }
        }
      }
      if (more) {
        *(bf16x8*)&Kl[cur ^ 1][srow * 72 + scol] = nk;
        *(bf16x8*)&Vl[cur ^ 1][srow * 72 + scol] = nv;
      }
      __syncthreads();
      cur ^= 1;
    }

    // ---- epilogue: combine l across lane pairs, normalize, store O ----
    const float ltot = lrun + __shfl_xor(lrun, 32);
    const float inv = 1.f / ltot;
    const size_t rowb = ((size_t)(bh >> 4) * T_ + qb + q5) * DEMB_ + (bh & 15) * HD_;
#pragma unroll
    for (int g = 0; g < 4; ++g) {
      bf16x4 st0, st1;
#pragma unroll
      for (int j = 0; j < 4; ++j) {
        st0[j] = tob(o0[4 * g + j] * inv);
        st1[j] = tob(o1[4 * g + j] * inv);
      }
      *(bf16x4*)&ob[rowb + 8 * g + 4 * hi]      = st0;
      *(bf16x4*)&ob[rowb + 8 * g + 4 * hi + 32] = st1;
    }
  }
}

// ---------------- GEMM2: out = attn * w_o^T + b_o (fp32 out), 2-phase pipelined ----------------
__global__ __launch_bounds__(256) void gemm_out_kernel(const bf16_t* __restrict__ A,
                                                       const bf16_t* __restrict__ Bm,
                                                       const float* __restrict__ bo,
                                                       float* __restrict__ out) {
  constexpr int K = DEMB_;
  __shared__ __align__(16) bf16_t As[2][128 * 32];
  __shared__ __align__(16) bf16_t Bs[2][128 * 32];
  const int tid = threadIdx.x, w = tid >> 6, l = tid & 63;
  const int lh = l >> 4, lr = l & 15;
  const int m0 = blockIdx.y * 128, n0 = blockIdx.x * 128;
  const int ar0 = (w >> 1) * 64, bc0 = (w & 1) * 64;

  auto stage = [&](int k0, int buf) {
#pragma unroll
    for (int i = 0; i < 2; ++i) {
      const int c = i * 256 + w * 64 + l;
      const int row = c >> 2, col = (c & 3) * 8;
      gload16(A  + (size_t)(m0 + row) * K + k0 + col,
              (char*)&As[buf][0] + (size_t)(i * 256 + w * 64) * 16);
      gload16(Bm + (size_t)(n0 + row) * K + k0 + col,
              (char*)&Bs[buf][0] + (size_t)(i * 256 + w * 64) * 16);
    }
  };

  f32x4 acc[4][4] = {};
  stage(0, 0);
  __syncthreads();
  int cur = 0;
  for (int k0 = 0; k0 < K; k0 += 32) {
    if (k0 + 32 < K) stage(k0 + 32, cur ^ 1);
    bf16x8 af[4], bfv[4];
#pragma unroll
    for (int mi = 0; mi < 4; ++mi) af[mi]  = *(const bf16x8*)&As[cur][(ar0 + mi * 16 + lr) * 32 + lh * 8];
#pragma unroll
    for (int ni = 0; ni < 4; ++ni) bfv[ni] = *(const bf16x8*)&Bs[cur][(bc0 + ni * 16 + lr) * 32 + lh * 8];
#pragma unroll
    for (int mi = 0; mi < 4; ++mi)
#pragma unroll
      for (int ni = 0; ni < 4; ++ni)
        acc[mi][ni] = mfma16(af[mi], bfv[ni], acc[mi][ni]);
    __syncthreads();
    cur ^= 1;
  }
#pragma unroll
  for (int mi = 0; mi < 4; ++mi) {
#pragma unroll
    for (int r = 0; r < 4; ++r) {
      const int gm = m0 + ar0 + mi * 16 + lh * 4 + r;
#pragma unroll
      for (int ni = 0; ni < 4; ++ni) {
        const int gn = n0 + bc0 + ni * 16 + lr;
        out[(size_t)gm * DEMB_ + gn] = acc[mi][ni][r] + bo[gn];
      }
    }
  }
}

extern "C" void kernel_launch(void* const* d_in, const int* in_sizes, int n_in,
                              void* d_out, int out_size, void* d_ws, size_t ws_size,
                              hipStream_t stream) {
  (void)in_sizes; (void)n_in; (void)out_size; (void)ws_size;
  const float* x     = (const float*)d_in[0];
  const float* w_qkv = (const float*)d_in[1];
  const float* w_o   = (const float*)d_in[2];
  const float* b_o   = (const float*)d_in[3];
  float* out = (float*)d_out;

  // Round-1-proven 75.5 MB workspace layout; vbuf holds V^T [B,H,64,T].
  char* p = (char*)d_ws;
  bf16_t* xb    = (bf16_t*)p; p += (size_t)M_ * DIN_ * 2;
  bf16_t* wqkvb = (bf16_t*)p; p += (size_t)NQKV_ * DIN_ * 2;
  bf16_t* wob   = (bf16_t*)p; p += (size_t)DEMB_ * DEMB_ * 2;
  bf16_t* qbuf  = (bf16_t*)p; p += (size_t)B_ * H_ * T_ * HD_ * 2;
  bf16_t* kbuf  = (bf16_t*)p; p += (size_t)B_ * H_ * T_ * HD_ * 2;
  bf16_t* vbuf  = (bf16_t*)p; p += (size_t)B_ * H_ * T_ * HD_ * 2;
  bf16_t* attnb = xb;    // x dead after gemm1

  cast_kernel<<<(M_ * DIN_) / 1024, 256, 0, stream>>>(x, xb);
  cast_kernel<<<(NQKV_ * DIN_) / 1024, 256, 0, stream>>>(w_qkv, wqkvb);
  cast_kernel<<<(DEMB_ * DEMB_) / 1024, 256, 0, stream>>>(w_o, wob);
  gemm_qkv_kernel<<<dim3(NQKV_ / 128, M_ / 128), 256, 0, stream>>>(xb, wqkvb, qbuf, kbuf, vbuf);
  attn2_kernel<<<256, 512, 0, stream>>>(qbuf, kbuf, vbuf, attnb);
  gemm_out_kernel<<<dim3(DEMB_ / 128, M_ / 128), 256, 0, stream>>>(attnb, wob, b_o, out);
}